// Round 10
// baseline (2389.040 us; speedup 1.0000x reference)
//
#include <hip/hip_runtime.h>

#define NBLKA 2048

__device__ __forceinline__ unsigned encf(float x) {
    unsigned u = __float_as_uint(x);
    return (u & 0x80000000u) ? ~u : (u | 0x80000000u);
}
__device__ __forceinline__ float decf(unsigned u) {
    u = (u & 0x80000000u) ? (u & 0x7FFFFFFFu) : ~u;
    return __uint_as_float(u);
}
__device__ __forceinline__ unsigned bf16rne(float f) {
    unsigned u = __float_as_uint(f);
    return (u + 0x7FFFu + ((u >> 16) & 1u)) >> 16;
}

// ============ CSR build: 512-node buckets, deterministic matrix scan ============

__global__ __launch_bounds__(256) void passA_k(const int* __restrict__ dst, int E,
                                               int* __restrict__ cntMat, int bshift,
                                               int nblk, int nb2) {
    __shared__ int hist[512];
    hist[threadIdx.x] = 0; hist[threadIdx.x + 256] = 0;
    __syncthreads();
    int base = blockIdx.x * 4096;
#pragma unroll
    for (int r = 0; r < 16; r++) {
        int i = base + threadIdx.x + r * 256;
        if (i < E) atomicAdd(&hist[dst[i] >> bshift], 1);
    }
    __syncthreads();
    for (int bk = threadIdx.x; bk < nb2; bk += 256)
        cntMat[bk * nblk + blockIdx.x] = hist[bk];
}

__global__ void scanA_k(int* __restrict__ data, int total, int* __restrict__ chunkTot) {
    __shared__ int sd[256];
    int tid = threadIdx.x;
    int base = blockIdx.x * 2048 + tid * 8;
    int v[8]; int s = 0;
#pragma unroll
    for (int r = 0; r < 8; r++) {
        int idx = base + r;
        int x = (idx < total) ? data[idx] : 0;
        s += x; v[r] = s;
    }
    sd[tid] = s; __syncthreads();
    for (int off = 1; off < 256; off <<= 1) {
        int x = (tid >= off) ? sd[tid - off] : 0;
        __syncthreads();
        sd[tid] += x;
        __syncthreads();
    }
    int prev = (tid > 0) ? sd[tid - 1] : 0;
#pragma unroll
    for (int r = 0; r < 8; r++) {
        int idx = base + r;
        if (idx < total) data[idx] = v[r] + prev;
    }
    if (tid == 255) chunkTot[blockIdx.x] = sd[255];
}

__global__ void scanB_k(const int* __restrict__ chunkTot, int nchunk, int* __restrict__ chunkOff) {
    __shared__ int sd[256];
    int tid = threadIdx.x;
    int v = (tid < nchunk) ? chunkTot[tid] : 0;
    sd[tid] = v; __syncthreads();
    for (int off = 1; off < 256; off <<= 1) {
        int x = (tid >= off) ? sd[tid - off] : 0;
        __syncthreads();
        sd[tid] += x;
        __syncthreads();
    }
    if (tid < nchunk) chunkOff[tid] = sd[tid] - v;
}

__global__ void scanC2_k(int* __restrict__ data, int total, const int* __restrict__ chunkOff) {
    int off = chunkOff[blockIdx.x];
    int base = blockIdx.x * 2048 + threadIdx.x * 8;
#pragma unroll
    for (int r = 0; r < 8; r++) {
        int idx = base + r;
        if (idx < total) data[idx] += off;
    }
}

__global__ __launch_bounds__(256) void passB_k(const int* __restrict__ ei,
                                               const int* __restrict__ ety, int E,
                                               const int* __restrict__ cntScan,
                                               unsigned* __restrict__ binned,
                                               int bshift, int sBits, int nblk, int nb2) {
    __shared__ unsigned stage[4096];
    __shared__ unsigned short bkid[4096];
    __shared__ int hist[512], sd[256], cursor[512], rebase[512];
    int tid = threadIdx.x;
    int base = blockIdx.x * 4096;
    hist[tid] = 0; hist[tid + 256] = 0;
    __syncthreads();

    unsigned ent[16];
    int bk[16];
    int lowmask = (1 << bshift) - 1;
    int dshift = sBits + 1;
#pragma unroll
    for (int r = 0; r < 16; r++) {
        int i = base + tid + r * 256;
        if (i < E) {
            int s = ei[i];
            int d = ei[E + i];
            int t = ety[i];
            ent[r] = ((unsigned)(d & lowmask) << dshift) | ((unsigned)t << sBits) | (unsigned)s;
            bk[r] = d >> bshift;
            atomicAdd(&hist[bk[r]], 1);
        } else bk[r] = -1;
    }
    __syncthreads();

    int v0 = hist[2 * tid], v1 = hist[2 * tid + 1];
    int sum2 = v0 + v1;
    sd[tid] = sum2; __syncthreads();
    for (int off = 1; off < 256; off <<= 1) {
        int x = (tid >= off) ? sd[tid - off] : 0;
        __syncthreads();
        sd[tid] += x;
        __syncthreads();
    }
    int exclPair = sd[tid] - sum2;
    __syncthreads();
    cursor[2 * tid] = exclPair;
    cursor[2 * tid + 1] = exclPair + v0;
    int b0 = 2 * tid, b1 = 2 * tid + 1;
    rebase[b0] = (b0 < nb2 && v0 > 0) ? (cntScan[b0 * nblk + blockIdx.x] - v0) - exclPair : 0;
    rebase[b1] = (b1 < nb2 && v1 > 0) ? (cntScan[b1 * nblk + blockIdx.x] - v1) - (exclPair + v0) : 0;
    __syncthreads();

#pragma unroll
    for (int r = 0; r < 16; r++) {
        if (bk[r] >= 0) {
            int p = atomicAdd(&cursor[bk[r]], 1);
            stage[p] = ent[r];
            bkid[p] = (unsigned short)bk[r];
        }
    }
    __syncthreads();

    int cnt = E - base; if (cnt > 4096) cnt = 4096;
    for (int i = tid; i < cnt; i += 256)
        binned[rebase[bkid[i]] + i] = stage[i];
}

__global__ __launch_bounds__(256) void passC_k(const unsigned* __restrict__ binned,
                                               const int* __restrict__ cntScan,
                                               int nblk, int* __restrict__ rowptr,
                                               unsigned* __restrict__ sorted,
                                               int N, int E, int bshift, int sBits,
                                               int nb2) {
    __shared__ int hist[512], cursor[512], sd[256];
    int tid = threadIdx.x;
    int b = blockIdx.x;
    int s = (b == 0) ? 0 : cntScan[b * nblk - 1];
    int e = cntScan[(b + 1) * nblk - 1];
    int nodeBase = b << bshift;
    int dshift = sBits + 1;

    hist[tid] = 0; hist[tid + 256] = 0;
    __syncthreads();
    for (int i = s + tid; i < e; i += 256)
        atomicAdd(&hist[(int)(binned[i] >> dshift)], 1);
    __syncthreads();

    int v0 = hist[2 * tid], v1 = hist[2 * tid + 1];
    int sum2 = v0 + v1;
    sd[tid] = sum2; __syncthreads();
    for (int off = 1; off < 256; off <<= 1) {
        int x = (tid >= off) ? sd[tid - off] : 0;
        __syncthreads();
        sd[tid] += x;
        __syncthreads();
    }
    int exclPair = sd[tid] - sum2;
    __syncthreads();
    cursor[2 * tid] = exclPair;
    cursor[2 * tid + 1] = exclPair + v0;
    int n0 = nodeBase + 2 * tid, n1 = nodeBase + 2 * tid + 1;
    if (n0 < N) rowptr[n0] = s + exclPair;
    if (n1 < N) rowptr[n1] = s + exclPair + v0;
    __syncthreads();

    for (int i = s + tid; i < e; i += 256) {
        unsigned en = binned[i];
        int ln = (int)(en >> dshift);
        int p = atomicAdd(&cursor[ln], 1);
        sorted[s + p] = en;
    }
    if (b == nb2 - 1 && tid == 0) rowptr[N] = E;
}

// prep: copy x->bf16 P (+sentinels), init pool buffers, zero layer counters
__global__ void prep_k(const float* __restrict__ x, unsigned* __restrict__ P,
                       unsigned* __restrict__ Q, int N,
                       unsigned* __restrict__ maxb, float* __restrict__ sumb, int G64,
                       int* __restrict__ cnts) {
    int i = blockIdx.x * 256 + threadIdx.x;
    int tot = N * 16;
    if (i < tot) {
        float2 v = ((const float2*)x)[i];
        P[i] = bf16rne(v.x) | (bf16rne(v.y) << 16);
    }
    if (i < 16) {
        unsigned sp = bf16rne(-1e30f) | (bf16rne(-1e30f) << 16);
        P[tot + i] = sp;
        Q[tot + i] = sp;
    }
    if (i < G64) { maxb[i] = 0x007FFFFFu; sumb[i] = 0.f; }
    if (i < 8) cnts[i] = 0;
}

// ---------- layer A: gather+MLP1 + fused BN-stat reduce (last-block) ----------
__global__ __launch_bounds__(256) void layerA_k(
    const unsigned* __restrict__ hin, const int* __restrict__ rowptr,
    const unsigned* __restrict__ sorted, const float* __restrict__ emb,
    const float* __restrict__ W1, const float* __restrict__ b1,
    const float* __restrict__ gamma, const float* __restrict__ beta,
    float* __restrict__ tout, float* __restrict__ partial,
    float* __restrict__ bn_ac, int* __restrict__ counter,
    int Nn, int sBits, unsigned sentw, float invN)
{
    float2* tout2 = (float2*)tout;
    int tid = threadIdx.x;
    int gl = tid & 31;
    int c = gl & 15;            // channel-pair index
    int slot = gl >> 4;         // edge slot / k-half
    int grp = tid >> 5;
    unsigned smask = (1u << sBits) - 1u;

    float2 w1c[16];
#pragma unroll
    for (int kk = 0; kk < 16; kk++)
        w1c[kk] = *(const float2*)&W1[(16 * slot + kk) * 32 + 2 * c];
    float2 b1p = *(const float2*)&b1[2 * c];
    float2 e0p = *(const float2*)&emb[2 * c];
    float2 e1p = *(const float2*)&emb[32 + 2 * c];

    __shared__ float zl[8][32];
    __shared__ float ls[8][32], lq[8][32];
    __shared__ float rd[4][64];
    __shared__ int isLast;

    float2 bsum = {0.f, 0.f}, bsq = {0.f, 0.f};

    int gid0 = (blockIdx.x * 256 + tid) >> 5;
    int nG = (gridDim.x * 256) >> 5;

    for (int n = gid0; n < Nn; n += nG) {
        int es = rowptr[n], ee = rowptr[n + 1];
        float accx = 0.f, accy = 0.f;
        for (int e0 = es; e0 < ee; e0 += 32) {
            int idx = e0 + gl;
            unsigned pv = (idx < ee) ? sorted[idx] : sentw;
#pragma unroll
            for (int kk = 0; kk < 16; kk++) {
                unsigned p = (unsigned)__shfl((int)pv, kk, 16);
                unsigned s = p & smask;
                unsigned w = hin[s * 16u + (unsigned)c];
                float hx = __uint_as_float(w << 16);
                float hy = __uint_as_float(w & 0xFFFF0000u);
                bool t1 = ((p >> sBits) & 1u) != 0u;
                float evx = t1 ? e1p.x : e0p.x;
                float evy = t1 ? e1p.y : e0p.y;
                accx += fmaxf(hx + evx, 0.f);
                accy += fmaxf(hy + evy, 0.f);
            }
        }
        accx += __shfl_xor(accx, 16);
        accy += __shfl_xor(accy, 16);
        unsigned wn = hin[(unsigned)n * 16u + (unsigned)c];
        accx += __uint_as_float(wn << 16);
        accy += __uint_as_float(wn & 0xFFFF0000u);

        if (slot == 0) { zl[grp][2 * c] = accx; zl[grp][2 * c + 1] = accy; }
        float tx = 0.f, ty = 0.f;
#pragma unroll
        for (int kk = 0; kk < 16; kk++) {
            float zk = zl[grp][16 * slot + kk];
            tx = fmaf(zk, w1c[kk].x, tx);
            ty = fmaf(zk, w1c[kk].y, ty);
        }
        tx += __shfl_xor(tx, 16);
        ty += __shfl_xor(ty, 16);
        tx += b1p.x; ty += b1p.y;
        if (slot == 0) { float2 tp; tp.x = tx; tp.y = ty; tout2[(unsigned)n * 16u + (unsigned)c] = tp; }
        bsum.x += tx; bsum.y += ty;
        bsq.x = fmaf(tx, tx, bsq.x);
        bsq.y = fmaf(ty, ty, bsq.y);
    }

    if (slot == 0) {
        ls[grp][2 * c] = bsum.x; ls[grp][2 * c + 1] = bsum.y;
        lq[grp][2 * c] = bsq.x;  lq[grp][2 * c + 1] = bsq.y;
    }
    __syncthreads();
    if (tid < 32) {
        float s = 0.f, q = 0.f;
#pragma unroll
        for (int r = 0; r < 8; r++) { s += ls[r][tid]; q += lq[r][tid]; }
        partial[blockIdx.x * 64 + tid] = s;
        partial[blockIdx.x * 64 + 32 + tid] = q;
    }
    __syncthreads();
    __threadfence();
    if (tid == 0) {
        int prev = atomicAdd(counter, 1);
        isLast = (prev == (int)gridDim.x - 1);
    }
    __syncthreads();
    if (isLast) {
        __threadfence();
        int cc = tid & 63, q = tid >> 6;
        float s = 0.f;
        for (int r = q; r < NBLKA; r += 4) s += partial[r * 64 + cc];
        rd[q][cc] = s;
        __syncthreads();
        if (tid < 32) {
            float mu = (rd[0][tid] + rd[1][tid] + rd[2][tid] + rd[3][tid]) * invN;
            float sq = (rd[0][tid + 32] + rd[1][tid + 32] + rd[2][tid + 32] + rd[3][tid + 32]) * invN;
            float var = sq - mu * mu;
            float a = gamma[tid] * rsqrtf(var + 1e-5f);
            bn_ac[tid] = a;
            bn_ac[32 + tid] = beta[tid] - a * mu;
        }
    }
}

// ---------- layer B (1-4): relu(bn(t)) @ W2 + b2, +relu, write packed bf16 ----------
__global__ __launch_bounds__(256) void layerB32_k(
    const float* __restrict__ tin, const float* __restrict__ bn_ac,
    const float* __restrict__ W2, const float* __restrict__ b2,
    unsigned* __restrict__ hout, int Nn)
{
    int tid = threadIdx.x;
    int j = tid & 31, grp = tid >> 5;
    float a = bn_ac[j], c = bn_ac[32 + j];
    float wc[32];
#pragma unroll
    for (int k = 0; k < 32; k++) wc[k] = W2[k * 32 + j];
    float bj = b2[j];
    for (int n = blockIdx.x * 8 + grp; n < Nn; n += gridDim.x * 8) {
        float t = tin[n * 32 + j];
        float u = fmaxf(fmaf(a, t, c), 0.f);
        float o = bj;
#pragma unroll
        for (int k = 0; k < 32; k++) o = fmaf(__shfl(u, k, 32), wc[k], o);
        unsigned b = bf16rne(fmaxf(o, 0.f));
        unsigned nb = (unsigned)__shfl_xor((int)b, 1, 32);
        if ((j & 1) == 0) hout[(unsigned)n * 16u + (unsigned)(j >> 1)] = b | (nb << 16);
    }
}

// ---------- layer B5 + pooling fused: conv5 outputs pooled in-register ----------
__global__ __launch_bounds__(256) void layerB64pool_k(
    const float* __restrict__ tin, const float* __restrict__ bn_ac,
    const float* __restrict__ W2, const float* __restrict__ b2,
    const int* __restrict__ batch,
    unsigned* __restrict__ maxb, float* __restrict__ sumb, int Nn)
{
    int tid = threadIdx.x;
    int j = tid & 31, grp = tid >> 5;
    float a = bn_ac[j], c = bn_ac[32 + j];
    float wlo[32], whi[32];
#pragma unroll
    for (int k = 0; k < 32; k++) { wlo[k] = W2[k * 64 + j]; whi[k] = W2[k * 64 + 32 + j]; }
    float blo = b2[j], bhi = b2[32 + j];

    int n0 = (blockIdx.x * 8 + grp) * 64;
    if (n0 >= Nn) return;
    int nend = n0 + 64; if (nend > Nn) nend = Nn;

    int curg = -1;
    float mxl = 0.f, mxh = 0.f, sml = 0.f, smh = 0.f;
    for (int n = n0; n < nend; n++) {
        float t = tin[n * 32 + j];
        float u = fmaxf(fmaf(a, t, c), 0.f);
        float olo = blo, ohi = bhi;
#pragma unroll
        for (int k = 0; k < 32; k++) {
            float uk = __shfl(u, k, 32);
            olo = fmaf(uk, wlo[k], olo);
            ohi = fmaf(uk, whi[k], ohi);
        }
        int gn = batch[n];
        if (gn != curg) {
            if (curg >= 0) {
                atomicMax(&maxb[curg * 64 + j], encf(mxl));
                atomicMax(&maxb[curg * 64 + 32 + j], encf(mxh));
                atomicAdd(&sumb[curg * 64 + j], sml);
                atomicAdd(&sumb[curg * 64 + 32 + j], smh);
            }
            curg = gn; mxl = olo; mxh = ohi; sml = olo; smh = ohi;
        } else {
            mxl = fmaxf(mxl, olo); mxh = fmaxf(mxh, ohi);
            sml += olo; smh += ohi;
        }
    }
    if (curg >= 0) {
        atomicMax(&maxb[curg * 64 + j], encf(mxl));
        atomicMax(&maxb[curg * 64 + 32 + j], encf(mxh));
        atomicAdd(&sumb[curg * 64 + j], sml);
        atomicAdd(&sumb[curg * 64 + 32 + j], smh);
    }
}

__global__ void final_k(const unsigned* __restrict__ maxb, const float* __restrict__ sumb,
                        const int* __restrict__ batch, int Nn, float* __restrict__ out)
{
    int g = blockIdx.x, tid = threadIdx.x;
    int a = 0, b = Nn;
    while (a < b) { int m = (a + b) >> 1; if (batch[m] < g) a = m + 1; else b = m; }
    int lo0 = a;
    a = 0; b = Nn;
    while (a < b) { int m = (a + b) >> 1; if (batch[m] < g + 1) a = m + 1; else b = m; }
    int hi0 = a;
    float inv = 1.f / fmaxf((float)(hi0 - lo0), 1.f);
    if (tid < 64) out[g * 128 + tid] = decf(maxb[g * 64 + tid]);
    else          out[g * 128 + tid] = sumb[g * 64 + (tid - 64)] * inv;
}

extern "C" void kernel_launch(void* const* d_in, const int* in_sizes, int n_in,
                              void* d_out, int out_size, void* d_ws, size_t ws_size,
                              hipStream_t stream) {
    const float* x    = (const float*)d_in[0];
    const int*   ei   = (const int*)d_in[1];
    const int*   ety  = (const int*)d_in[2];
    const int*   batch= (const int*)d_in[3];
    const float* emb  = (const float*)d_in[4];
    const float* W1s  = (const float*)d_in[5];
    const float* b1s  = (const float*)d_in[6];
    const float* g1s  = (const float*)d_in[7];
    const float* be1s = (const float*)d_in[8];
    const float* W2s  = (const float*)d_in[9];
    const float* b2s  = (const float*)d_in[10];
    const float* w15  = (const float*)d_in[11];
    const float* b15  = (const float*)d_in[12];
    const float* g5   = (const float*)d_in[13];
    const float* be5  = (const float*)d_in[14];
    const float* w25  = (const float*)d_in[15];
    const float* b25  = (const float*)d_in[16];

    int N = in_sizes[0] / 32;
    int E = in_sizes[1] / 2;
    int G = out_size / 128;

    int sBits = 1; while ((1 << sBits) < N + 1) sBits++;            // 18
    int bshift = 0; while (((N - 1) >> bshift) >= 512) bshift++;    // 9
    int nb2 = ((N - 1) >> bshift) + 1;                              // 391
    int nblkE = (E + 4095) / 4096;                                  // 977

    char* wsb = (char*)d_ws;
    size_t o = 0;
    size_t hPkBytes = (size_t)(N + 1) * 16 * 4;
    size_t tbBytes = (size_t)N * 32 * 4;
    size_t binBytes = (size_t)E * 4;
    size_t rtb = tbBytes > binBytes ? tbBytes : binBytes;
    unsigned* P      = (unsigned*)(wsb + o); o += hPkBytes;
    unsigned* Q      = (unsigned*)(wsb + o); o += hPkBytes;
    float*    tb     = (float*)(wsb + o);
    unsigned* binned = (unsigned*)(wsb + o);        // alias: dead before layerA L0
    o += rtb;
    int*      rowptr = (int*)(wsb + o);   o += ((size_t)N + 2) * 4;
    unsigned* sorted = (unsigned*)(wsb + o); o += (size_t)E * 4;
    int*      chunkTot = (int*)(wsb + o); o += 1024;
    int*      chunkOff = (int*)(wsb + o); o += 1024;
    float*    partial  = (float*)(wsb + o); o += (size_t)NBLKA * 64 * 4;
    float*    bn_ac    = (float*)(wsb + o); o += 64 * 4;
    int*      cnts     = (int*)(wsb + o); o += 32;
    unsigned* maxb     = (unsigned*)(wsb + o); o += (size_t)G * 64 * 4;
    float*    sumb     = (float*)(wsb + o); o += (size_t)G * 64 * 4;
    int*      cntMat   = (int*)(wsb + o); o += (size_t)nb2 * nblkE * 4;

    // ---- CSR build ----
    passA_k<<<nblkE, 256, 0, stream>>>(ei + E, E, cntMat, bshift, nblkE, nb2);
    int total2 = nb2 * nblkE;
    int nchunk2 = (total2 + 2047) / 2048;
    scanA_k<<<nchunk2, 256, 0, stream>>>(cntMat, total2, chunkTot);
    scanB_k<<<1, 256, 0, stream>>>(chunkTot, nchunk2, chunkOff);
    scanC2_k<<<nchunk2, 256, 0, stream>>>(cntMat, total2, chunkOff);
    passB_k<<<nblkE, 256, 0, stream>>>(ei, ety, E, cntMat, binned, bshift, sBits, nblkE, nb2);
    passC_k<<<nb2, 256, 0, stream>>>(binned, cntMat, nblkE, rowptr, sorted, N, E, bshift, sBits, nb2);
    prep_k<<<(N * 16 + 255) / 256, 256, 0, stream>>>(x, P, Q, N, maxb, sumb, G * 64, cnts);

    unsigned sentw = (unsigned)N;
    float invN = 1.f / (float)N;

    // ---- 5 GINE layers (ping-pong P<->Q; BN reduce fused into layerA tail) ----
    unsigned* inb = P;
    unsigned* outb = Q;
    for (int L = 0; L < 5; ++L) {
        const float* W1 = (L < 4) ? W1s + L * 1024 : w15;
        const float* b1 = (L < 4) ? b1s + L * 32  : b15;
        const float* ga = (L < 4) ? g1s + L * 32  : g5;
        const float* be = (L < 4) ? be1s + L * 32 : be5;
        const float* W2 = (L < 4) ? W2s + L * 1024 : w25;
        const float* b2 = (L < 4) ? b2s + L * 32  : b25;

        layerA_k<<<NBLKA, 256, 0, stream>>>(inb, rowptr, sorted, emb, W1, b1, ga, be,
                                            tb, partial, bn_ac, cnts + L, N, sBits, sentw, invN);
        if (L < 4) {
            layerB32_k<<<1024, 256, 0, stream>>>(tb, bn_ac, W2, b2, outb, N);
            unsigned* tmp = inb; inb = outb; outb = tmp;
        } else {
            layerB64pool_k<<<(N + 511) / 512, 256, 0, stream>>>(tb, bn_ac, W2, b2, batch, maxb, sumb, N);
        }
    }

    // ---- output ----
    final_k<<<G, 128, 0, stream>>>(maxb, sumb, batch, N, (float*)d_out);
}

// Round 11
// 688.602 us; speedup vs baseline: 3.4694x; 3.4694x over previous
//
#include <hip/hip_runtime.h>

#define NBLKA 2048

__device__ __forceinline__ unsigned encf(float x) {
    unsigned u = __float_as_uint(x);
    return (u & 0x80000000u) ? ~u : (u | 0x80000000u);
}
__device__ __forceinline__ float decf(unsigned u) {
    u = (u & 0x80000000u) ? (u & 0x7FFFFFFFu) : ~u;
    return __uint_as_float(u);
}
__device__ __forceinline__ unsigned bf16rne(float f) {
    unsigned u = __float_as_uint(f);
    return (u + 0x7FFFu + ((u >> 16) & 1u)) >> 16;
}

// ============ CSR build: 512-node buckets, deterministic matrix scan ============

__global__ __launch_bounds__(256) void passA_k(const int* __restrict__ dst, int E,
                                               int* __restrict__ cntMat, int bshift,
                                               int nblk, int nb2) {
    __shared__ int hist[512];
    hist[threadIdx.x] = 0; hist[threadIdx.x + 256] = 0;
    __syncthreads();
    int base = blockIdx.x * 4096;
#pragma unroll
    for (int r = 0; r < 16; r++) {
        int i = base + threadIdx.x + r * 256;
        if (i < E) atomicAdd(&hist[dst[i] >> bshift], 1);
    }
    __syncthreads();
    for (int bk = threadIdx.x; bk < nb2; bk += 256)
        cntMat[bk * nblk + blockIdx.x] = hist[bk];
}

__global__ void scanA_k(int* __restrict__ data, int total, int* __restrict__ chunkTot) {
    __shared__ int sd[256];
    int tid = threadIdx.x;
    int base = blockIdx.x * 2048 + tid * 8;
    int v[8]; int s = 0;
#pragma unroll
    for (int r = 0; r < 8; r++) {
        int idx = base + r;
        int x = (idx < total) ? data[idx] : 0;
        s += x; v[r] = s;
    }
    sd[tid] = s; __syncthreads();
    for (int off = 1; off < 256; off <<= 1) {
        int x = (tid >= off) ? sd[tid - off] : 0;
        __syncthreads();
        sd[tid] += x;
        __syncthreads();
    }
    int prev = (tid > 0) ? sd[tid - 1] : 0;
#pragma unroll
    for (int r = 0; r < 8; r++) {
        int idx = base + r;
        if (idx < total) data[idx] = v[r] + prev;
    }
    if (tid == 255) chunkTot[blockIdx.x] = sd[255];
}

__global__ void scanB_k(const int* __restrict__ chunkTot, int nchunk, int* __restrict__ chunkOff) {
    __shared__ int sd[256];
    int tid = threadIdx.x;
    int v = (tid < nchunk) ? chunkTot[tid] : 0;
    sd[tid] = v; __syncthreads();
    for (int off = 1; off < 256; off <<= 1) {
        int x = (tid >= off) ? sd[tid - off] : 0;
        __syncthreads();
        sd[tid] += x;
        __syncthreads();
    }
    if (tid < nchunk) chunkOff[tid] = sd[tid] - v;
}

__global__ void scanC2_k(int* __restrict__ data, int total, const int* __restrict__ chunkOff) {
    int off = chunkOff[blockIdx.x];
    int base = blockIdx.x * 2048 + threadIdx.x * 8;
#pragma unroll
    for (int r = 0; r < 8; r++) {
        int idx = base + r;
        if (idx < total) data[idx] += off;
    }
}

__global__ __launch_bounds__(256) void passB_k(const int* __restrict__ ei,
                                               const int* __restrict__ ety, int E,
                                               const int* __restrict__ cntScan,
                                               unsigned* __restrict__ binned,
                                               int bshift, int sBits, int nblk, int nb2) {
    __shared__ unsigned stage[4096];
    __shared__ unsigned short bkid[4096];
    __shared__ int hist[512], sd[256], cursor[512], rebase[512];
    int tid = threadIdx.x;
    int base = blockIdx.x * 4096;
    hist[tid] = 0; hist[tid + 256] = 0;
    __syncthreads();

    unsigned ent[16];
    int bk[16];
    int lowmask = (1 << bshift) - 1;
    int dshift = sBits + 1;
#pragma unroll
    for (int r = 0; r < 16; r++) {
        int i = base + tid + r * 256;
        if (i < E) {
            int s = ei[i];
            int d = ei[E + i];
            int t = ety[i];
            ent[r] = ((unsigned)(d & lowmask) << dshift) | ((unsigned)t << sBits) | (unsigned)s;
            bk[r] = d >> bshift;
            atomicAdd(&hist[bk[r]], 1);
        } else bk[r] = -1;
    }
    __syncthreads();

    int v0 = hist[2 * tid], v1 = hist[2 * tid + 1];
    int sum2 = v0 + v1;
    sd[tid] = sum2; __syncthreads();
    for (int off = 1; off < 256; off <<= 1) {
        int x = (tid >= off) ? sd[tid - off] : 0;
        __syncthreads();
        sd[tid] += x;
        __syncthreads();
    }
    int exclPair = sd[tid] - sum2;
    __syncthreads();
    cursor[2 * tid] = exclPair;
    cursor[2 * tid + 1] = exclPair + v0;
    int b0 = 2 * tid, b1 = 2 * tid + 1;
    rebase[b0] = (b0 < nb2 && v0 > 0) ? (cntScan[b0 * nblk + blockIdx.x] - v0) - exclPair : 0;
    rebase[b1] = (b1 < nb2 && v1 > 0) ? (cntScan[b1 * nblk + blockIdx.x] - v1) - (exclPair + v0) : 0;
    __syncthreads();

#pragma unroll
    for (int r = 0; r < 16; r++) {
        if (bk[r] >= 0) {
            int p = atomicAdd(&cursor[bk[r]], 1);
            stage[p] = ent[r];
            bkid[p] = (unsigned short)bk[r];
        }
    }
    __syncthreads();

    int cnt = E - base; if (cnt > 4096) cnt = 4096;
    for (int i = tid; i < cnt; i += 256)
        binned[rebase[bkid[i]] + i] = stage[i];
}

__global__ __launch_bounds__(256) void passC_k(const unsigned* __restrict__ binned,
                                               const int* __restrict__ cntScan,
                                               int nblk, int* __restrict__ rowptr,
                                               unsigned* __restrict__ sorted,
                                               int N, int E, int bshift, int sBits,
                                               int nb2) {
    __shared__ int hist[512], cursor[512], sd[256];
    int tid = threadIdx.x;
    int b = blockIdx.x;
    int s = (b == 0) ? 0 : cntScan[b * nblk - 1];
    int e = cntScan[(b + 1) * nblk - 1];
    int nodeBase = b << bshift;
    int dshift = sBits + 1;

    hist[tid] = 0; hist[tid + 256] = 0;
    __syncthreads();
    for (int i = s + tid; i < e; i += 256)
        atomicAdd(&hist[(int)(binned[i] >> dshift)], 1);
    __syncthreads();

    int v0 = hist[2 * tid], v1 = hist[2 * tid + 1];
    int sum2 = v0 + v1;
    sd[tid] = sum2; __syncthreads();
    for (int off = 1; off < 256; off <<= 1) {
        int x = (tid >= off) ? sd[tid - off] : 0;
        __syncthreads();
        sd[tid] += x;
        __syncthreads();
    }
    int exclPair = sd[tid] - sum2;
    __syncthreads();
    cursor[2 * tid] = exclPair;
    cursor[2 * tid + 1] = exclPair + v0;
    int n0 = nodeBase + 2 * tid, n1 = nodeBase + 2 * tid + 1;
    if (n0 < N) rowptr[n0] = s + exclPair;
    if (n1 < N) rowptr[n1] = s + exclPair + v0;
    __syncthreads();

    for (int i = s + tid; i < e; i += 256) {
        unsigned en = binned[i];
        int ln = (int)(en >> dshift);
        int p = atomicAdd(&cursor[ln], 1);
        sorted[s + p] = en;
    }
    if (b == nb2 - 1 && tid == 0) rowptr[N] = E;
}

// prep: copy x->bf16 P (+sentinels), init pool buffers
__global__ void prep_k(const float* __restrict__ x, unsigned* __restrict__ P,
                       unsigned* __restrict__ Q, int N,
                       unsigned* __restrict__ maxb, float* __restrict__ sumb, int G64) {
    int i = blockIdx.x * 256 + threadIdx.x;
    int tot = N * 16;
    if (i < tot) {
        float2 v = ((const float2*)x)[i];
        P[i] = bf16rne(v.x) | (bf16rne(v.y) << 16);
    }
    if (i < 16) {
        unsigned sp = bf16rne(-1e30f) | (bf16rne(-1e30f) << 16);
        P[tot + i] = sp;
        Q[tot + i] = sp;
    }
    if (i < G64) { maxb[i] = 0x007FFFFFu; sumb[i] = 0.f; }
}

// ---------- layer A (round-9 proven body): 16 ch-lanes x 2 edge slots, bf16 h ----------
__global__ __launch_bounds__(256) void layerA_k(
    const unsigned* __restrict__ hin, const int* __restrict__ rowptr,
    const unsigned* __restrict__ sorted, const float* __restrict__ emb,
    const float* __restrict__ W1, const float* __restrict__ b1,
    float* __restrict__ tout, float* __restrict__ partial, int Nn, int sBits,
    unsigned sentw)
{
    float2* tout2 = (float2*)tout;
    int tid = threadIdx.x;
    int gl = tid & 31;
    int c = gl & 15;            // channel-pair index
    int slot = gl >> 4;         // edge slot / k-half
    int grp = tid >> 5;
    unsigned smask = (1u << sBits) - 1u;

    float2 w1c[16];
#pragma unroll
    for (int kk = 0; kk < 16; kk++)
        w1c[kk] = *(const float2*)&W1[(16 * slot + kk) * 32 + 2 * c];
    float2 b1p = *(const float2*)&b1[2 * c];
    float2 e0p = *(const float2*)&emb[2 * c];
    float2 e1p = *(const float2*)&emb[32 + 2 * c];

    __shared__ float zl[8][32];
    __shared__ float ls[8][32], lq[8][32];

    float2 bsum = {0.f, 0.f}, bsq = {0.f, 0.f};

    int gid0 = (blockIdx.x * 256 + tid) >> 5;
    int nG = (gridDim.x * 256) >> 5;

    for (int n = gid0; n < Nn; n += nG) {
        int es = rowptr[n], ee = rowptr[n + 1];
        float accx = 0.f, accy = 0.f;
        for (int e0 = es; e0 < ee; e0 += 32) {
            int idx = e0 + gl;
            unsigned pv = (idx < ee) ? sorted[idx] : sentw;
#pragma unroll
            for (int kk = 0; kk < 16; kk++) {
                unsigned p = (unsigned)__shfl((int)pv, kk, 16);
                unsigned s = p & smask;
                unsigned w = hin[s * 16u + (unsigned)c];
                float hx = __uint_as_float(w << 16);
                float hy = __uint_as_float(w & 0xFFFF0000u);
                bool t1 = ((p >> sBits) & 1u) != 0u;
                float evx = t1 ? e1p.x : e0p.x;
                float evy = t1 ? e1p.y : e0p.y;
                accx += fmaxf(hx + evx, 0.f);
                accy += fmaxf(hy + evy, 0.f);
            }
        }
        accx += __shfl_xor(accx, 16);
        accy += __shfl_xor(accy, 16);
        unsigned wn = hin[(unsigned)n * 16u + (unsigned)c];
        accx += __uint_as_float(wn << 16);
        accy += __uint_as_float(wn & 0xFFFF0000u);

        if (slot == 0) { zl[grp][2 * c] = accx; zl[grp][2 * c + 1] = accy; }
        float tx = 0.f, ty = 0.f;
#pragma unroll
        for (int kk = 0; kk < 16; kk++) {
            float zk = zl[grp][16 * slot + kk];
            tx = fmaf(zk, w1c[kk].x, tx);
            ty = fmaf(zk, w1c[kk].y, ty);
        }
        tx += __shfl_xor(tx, 16);
        ty += __shfl_xor(ty, 16);
        tx += b1p.x; ty += b1p.y;
        if (slot == 0) { float2 tp; tp.x = tx; tp.y = ty; tout2[(unsigned)n * 16u + (unsigned)c] = tp; }
        bsum.x += tx; bsum.y += ty;
        bsq.x = fmaf(tx, tx, bsq.x);
        bsq.y = fmaf(ty, ty, bsq.y);
    }

    if (slot == 0) {
        ls[grp][2 * c] = bsum.x; ls[grp][2 * c + 1] = bsum.y;
        lq[grp][2 * c] = bsq.x;  lq[grp][2 * c + 1] = bsq.y;
    }
    __syncthreads();
    if (tid < 32) {
        float s = 0.f, q = 0.f;
#pragma unroll
        for (int r = 0; r < 8; r++) { s += ls[r][tid]; q += lq[r][tid]; }
        partial[blockIdx.x * 64 + tid] = s;
        partial[blockIdx.x * 64 + 32 + tid] = q;
    }
}

// ---------- BN stat reduce, two-stage parallel ----------
__global__ __launch_bounds__(256) void bnred1_k(const float* __restrict__ partial,
                                                float* __restrict__ partial2) {
    __shared__ float sd[4][64];
    int tid = threadIdx.x;
    int c = tid & 63, q = tid >> 6;
    int rowBase = blockIdx.x * 32 + q * 8;
    float s = 0.f;
#pragma unroll
    for (int r = 0; r < 8; r++) s += partial[(rowBase + r) * 64 + c];
    sd[q][c] = s;
    __syncthreads();
    if (q == 0) partial2[blockIdx.x * 64 + c] = sd[0][c] + sd[1][c] + sd[2][c] + sd[3][c];
}

__global__ __launch_bounds__(256) void bnred2_k(const float* __restrict__ partial2,
                                                const float* __restrict__ gamma,
                                                const float* __restrict__ beta,
                                                float* __restrict__ bn_ac, float invN) {
    __shared__ float sd[4][64];
    int tid = threadIdx.x;
    int c = tid & 63, q = tid >> 6;
    float s = 0.f;
#pragma unroll
    for (int r = 0; r < 16; r++) s += partial2[(q * 16 + r) * 64 + c];
    sd[q][c] = s;
    __syncthreads();
    if (tid < 32) {
        float mu  = (sd[0][tid] + sd[1][tid] + sd[2][tid] + sd[3][tid]) * invN;
        float sq  = (sd[0][tid + 32] + sd[1][tid + 32] + sd[2][tid + 32] + sd[3][tid + 32]) * invN;
        float var = sq - mu * mu;
        float a = gamma[tid] * rsqrtf(var + 1e-5f);
        bn_ac[tid] = a;
        bn_ac[32 + tid] = beta[tid] - a * mu;
    }
}

// ---------- layer B (1-4): relu(bn(t)) @ W2 + b2, +relu, write packed bf16 ----------
__global__ __launch_bounds__(256) void layerB32_k(
    const float* __restrict__ tin, const float* __restrict__ bn_ac,
    const float* __restrict__ W2, const float* __restrict__ b2,
    unsigned* __restrict__ hout, int Nn)
{
    int tid = threadIdx.x;
    int j = tid & 31, grp = tid >> 5;
    float a = bn_ac[j], c = bn_ac[32 + j];
    float wc[32];
#pragma unroll
    for (int k = 0; k < 32; k++) wc[k] = W2[k * 32 + j];
    float bj = b2[j];
    for (int n = blockIdx.x * 8 + grp; n < Nn; n += gridDim.x * 8) {
        float t = tin[n * 32 + j];
        float u = fmaxf(fmaf(a, t, c), 0.f);
        float o = bj;
#pragma unroll
        for (int k = 0; k < 32; k++) o = fmaf(__shfl(u, k, 32), wc[k], o);
        unsigned b = bf16rne(fmaxf(o, 0.f));
        unsigned nb = (unsigned)__shfl_xor((int)b, 1, 32);
        if ((j & 1) == 0) hout[(unsigned)n * 16u + (unsigned)(j >> 1)] = b | (nb << 16);
    }
}

// ---------- layer B5 + pooling fused ----------
__global__ __launch_bounds__(256) void layerB64pool_k(
    const float* __restrict__ tin, const float* __restrict__ bn_ac,
    const float* __restrict__ W2, const float* __restrict__ b2,
    const int* __restrict__ batch,
    unsigned* __restrict__ maxb, float* __restrict__ sumb, int Nn)
{
    int tid = threadIdx.x;
    int j = tid & 31, grp = tid >> 5;
    float a = bn_ac[j], c = bn_ac[32 + j];
    float wlo[32], whi[32];
#pragma unroll
    for (int k = 0; k < 32; k++) { wlo[k] = W2[k * 64 + j]; whi[k] = W2[k * 64 + 32 + j]; }
    float blo = b2[j], bhi = b2[32 + j];

    int n0 = (blockIdx.x * 8 + grp) * 64;
    if (n0 >= Nn) return;
    int nend = n0 + 64; if (nend > Nn) nend = Nn;

    int curg = -1;
    float mxl = 0.f, mxh = 0.f, sml = 0.f, smh = 0.f;
    for (int n = n0; n < nend; n++) {
        float t = tin[n * 32 + j];
        float u = fmaxf(fmaf(a, t, c), 0.f);
        float olo = blo, ohi = bhi;
#pragma unroll
        for (int k = 0; k < 32; k++) {
            float uk = __shfl(u, k, 32);
            olo = fmaf(uk, wlo[k], olo);
            ohi = fmaf(uk, whi[k], ohi);
        }
        int gn = batch[n];
        if (gn != curg) {
            if (curg >= 0) {
                atomicMax(&maxb[curg * 64 + j], encf(mxl));
                atomicMax(&maxb[curg * 64 + 32 + j], encf(mxh));
                atomicAdd(&sumb[curg * 64 + j], sml);
                atomicAdd(&sumb[curg * 64 + 32 + j], smh);
            }
            curg = gn; mxl = olo; mxh = ohi; sml = olo; smh = ohi;
        } else {
            mxl = fmaxf(mxl, olo); mxh = fmaxf(mxh, ohi);
            sml += olo; smh += ohi;
        }
    }
    if (curg >= 0) {
        atomicMax(&maxb[curg * 64 + j], encf(mxl));
        atomicMax(&maxb[curg * 64 + 32 + j], encf(mxh));
        atomicAdd(&sumb[curg * 64 + j], sml);
        atomicAdd(&sumb[curg * 64 + 32 + j], smh);
    }
}

__global__ void final_k(const unsigned* __restrict__ maxb, const float* __restrict__ sumb,
                        const int* __restrict__ batch, int Nn, float* __restrict__ out)
{
    int g = blockIdx.x, tid = threadIdx.x;
    int a = 0, b = Nn;
    while (a < b) { int m = (a + b) >> 1; if (batch[m] < g) a = m + 1; else b = m; }
    int lo0 = a;
    a = 0; b = Nn;
    while (a < b) { int m = (a + b) >> 1; if (batch[m] < g + 1) a = m + 1; else b = m; }
    int hi0 = a;
    float inv = 1.f / fmaxf((float)(hi0 - lo0), 1.f);
    if (tid < 64) out[g * 128 + tid] = decf(maxb[g * 64 + tid]);
    else          out[g * 128 + tid] = sumb[g * 64 + (tid - 64)] * inv;
}

extern "C" void kernel_launch(void* const* d_in, const int* in_sizes, int n_in,
                              void* d_out, int out_size, void* d_ws, size_t ws_size,
                              hipStream_t stream) {
    const float* x    = (const float*)d_in[0];
    const int*   ei   = (const int*)d_in[1];
    const int*   ety  = (const int*)d_in[2];
    const int*   batch= (const int*)d_in[3];
    const float* emb  = (const float*)d_in[4];
    const float* W1s  = (const float*)d_in[5];
    const float* b1s  = (const float*)d_in[6];
    const float* g1s  = (const float*)d_in[7];
    const float* be1s = (const float*)d_in[8];
    const float* W2s  = (const float*)d_in[9];
    const float* b2s  = (const float*)d_in[10];
    const float* w15  = (const float*)d_in[11];
    const float* b15  = (const float*)d_in[12];
    const float* g5   = (const float*)d_in[13];
    const float* be5  = (const float*)d_in[14];
    const float* w25  = (const float*)d_in[15];
    const float* b25  = (const float*)d_in[16];

    int N = in_sizes[0] / 32;
    int E = in_sizes[1] / 2;
    int G = out_size / 128;

    int sBits = 1; while ((1 << sBits) < N + 1) sBits++;            // 18
    int bshift = 0; while (((N - 1) >> bshift) >= 512) bshift++;    // 9
    int nb2 = ((N - 1) >> bshift) + 1;                              // 391
    int nblkE = (E + 4095) / 4096;                                  // 977

    char* wsb = (char*)d_ws;
    size_t o = 0;
    size_t hPkBytes = (size_t)(N + 1) * 16 * 4;
    size_t tbBytes = (size_t)N * 32 * 4;
    size_t binBytes = (size_t)E * 4;
    size_t rtb = tbBytes > binBytes ? tbBytes : binBytes;
    unsigned* P      = (unsigned*)(wsb + o); o += hPkBytes;
    unsigned* Q      = (unsigned*)(wsb + o); o += hPkBytes;
    float*    tb     = (float*)(wsb + o);
    unsigned* binned = (unsigned*)(wsb + o);        // alias: dead before layerA L0
    o += rtb;
    int*      rowptr = (int*)(wsb + o);   o += ((size_t)N + 2) * 4;
    unsigned* sorted = (unsigned*)(wsb + o); o += (size_t)E * 4;
    int*      chunkTot = (int*)(wsb + o); o += 1024;
    int*      chunkOff = (int*)(wsb + o); o += 1024;
    float*    partial  = (float*)(wsb + o); o += (size_t)NBLKA * 64 * 4;
    float*    partial2 = (float*)(wsb + o); o += 64 * 64 * 4;
    float*    bn_ac    = (float*)(wsb + o); o += 64 * 4;
    unsigned* maxb     = (unsigned*)(wsb + o); o += (size_t)G * 64 * 4;
    float*    sumb     = (float*)(wsb + o); o += (size_t)G * 64 * 4;
    int*      cntMat   = (int*)(wsb + o); o += (size_t)nb2 * nblkE * 4;

    // ---- CSR build ----
    passA_k<<<nblkE, 256, 0, stream>>>(ei + E, E, cntMat, bshift, nblkE, nb2);
    int total2 = nb2 * nblkE;
    int nchunk2 = (total2 + 2047) / 2048;
    scanA_k<<<nchunk2, 256, 0, stream>>>(cntMat, total2, chunkTot);
    scanB_k<<<1, 256, 0, stream>>>(chunkTot, nchunk2, chunkOff);
    scanC2_k<<<nchunk2, 256, 0, stream>>>(cntMat, total2, chunkOff);
    passB_k<<<nblkE, 256, 0, stream>>>(ei, ety, E, cntMat, binned, bshift, sBits, nblkE, nb2);
    passC_k<<<nb2, 256, 0, stream>>>(binned, cntMat, nblkE, rowptr, sorted, N, E, bshift, sBits, nb2);
    prep_k<<<(N * 16 + 255) / 256, 256, 0, stream>>>(x, P, Q, N, maxb, sumb, G * 64);

    unsigned sentw = (unsigned)N;
    float invN = 1.f / (float)N;

    // ---- 5 GINE layers (ping-pong P<->Q) ----
    unsigned* inb = P;
    unsigned* outb = Q;
    for (int L = 0; L < 5; ++L) {
        const float* W1 = (L < 4) ? W1s + L * 1024 : w15;
        const float* b1 = (L < 4) ? b1s + L * 32  : b15;
        const float* ga = (L < 4) ? g1s + L * 32  : g5;
        const float* be = (L < 4) ? be1s + L * 32 : be5;
        const float* W2 = (L < 4) ? W2s + L * 1024 : w25;
        const float* b2 = (L < 4) ? b2s + L * 32  : b25;

        layerA_k<<<NBLKA, 256, 0, stream>>>(inb, rowptr, sorted, emb, W1, b1, tb, partial, N, sBits, sentw);
        bnred1_k<<<64, 256, 0, stream>>>(partial, partial2);
        bnred2_k<<<1, 256, 0, stream>>>(partial2, ga, be, bn_ac, invN);
        if (L < 4) {
            layerB32_k<<<1024, 256, 0, stream>>>(tb, bn_ac, W2, b2, outb, N);
            unsigned* tmp = inb; inb = outb; outb = tmp;
        } else {
            layerB64pool_k<<<(N + 511) / 512, 256, 0, stream>>>(tb, bn_ac, W2, b2, batch, maxb, sumb, N);
        }
    }

    // ---- output ----
    final_k<<<G, 128, 0, stream>>>(maxb, sumb, batch, N, (float*)d_out);
}

// Round 13
// 671.064 us; speedup vs baseline: 3.5601x; 1.0261x over previous
//
#include <hip/hip_runtime.h>
#include <hip/hip_fp16.h>

#define NBLKA 2048

typedef _Float16 f16x2 __attribute__((ext_vector_type(2)));

__device__ __forceinline__ unsigned encf(float x) {
    unsigned u = __float_as_uint(x);
    return (u & 0x80000000u) ? ~u : (u | 0x80000000u);
}
__device__ __forceinline__ float decf(unsigned u) {
    u = (u & 0x80000000u) ? (u & 0x7FFFFFFFu) : ~u;
    return __uint_as_float(u);
}

// ============ CSR build: 512-node buckets, deterministic matrix scan ============

__global__ __launch_bounds__(256) void passA_k(const int* __restrict__ dst, int E,
                                               int* __restrict__ cntMat, int bshift,
                                               int nblk, int nb2) {
    __shared__ int hist[512];
    hist[threadIdx.x] = 0; hist[threadIdx.x + 256] = 0;
    __syncthreads();
    int base = blockIdx.x * 4096;
#pragma unroll
    for (int r = 0; r < 16; r++) {
        int i = base + threadIdx.x + r * 256;
        if (i < E) atomicAdd(&hist[dst[i] >> bshift], 1);
    }
    __syncthreads();
    for (int bk = threadIdx.x; bk < nb2; bk += 256)
        cntMat[bk * nblk + blockIdx.x] = hist[bk];
}

__global__ void scanA_k(int* __restrict__ data, int total, int* __restrict__ chunkTot) {
    __shared__ int sd[256];
    int tid = threadIdx.x;
    int base = blockIdx.x * 2048 + tid * 8;
    int v[8]; int s = 0;
#pragma unroll
    for (int r = 0; r < 8; r++) {
        int idx = base + r;
        int x = (idx < total) ? data[idx] : 0;
        s += x; v[r] = s;
    }
    sd[tid] = s; __syncthreads();
    for (int off = 1; off < 256; off <<= 1) {
        int x = (tid >= off) ? sd[tid - off] : 0;
        __syncthreads();
        sd[tid] += x;
        __syncthreads();
    }
    int prev = (tid > 0) ? sd[tid - 1] : 0;
#pragma unroll
    for (int r = 0; r < 8; r++) {
        int idx = base + r;
        if (idx < total) data[idx] = v[r] + prev;
    }
    if (tid == 255) chunkTot[blockIdx.x] = sd[255];
}

// scanC3: each block re-scans chunkTot in LDS (nchunk<=256) and applies its offset
__global__ void scanC3_k(int* __restrict__ data, int total,
                         const int* __restrict__ chunkTot, int nchunk) {
    __shared__ int sd[256];
    int tid = threadIdx.x;
    int v = (tid < nchunk) ? chunkTot[tid] : 0;
    sd[tid] = v; __syncthreads();
    for (int off = 1; off < 256; off <<= 1) {
        int x = (tid >= off) ? sd[tid - off] : 0;
        __syncthreads();
        sd[tid] += x;
        __syncthreads();
    }
    int boff = (blockIdx.x > 0) ? sd[blockIdx.x - 1] : 0;
    int base = blockIdx.x * 2048 + tid * 8;
#pragma unroll
    for (int r = 0; r < 8; r++) {
        int idx = base + r;
        if (idx < total) data[idx] += boff;
    }
}

__global__ __launch_bounds__(256) void passB_k(const int* __restrict__ ei,
                                               const int* __restrict__ ety, int E,
                                               const int* __restrict__ cntScan,
                                               unsigned* __restrict__ binned,
                                               int bshift, int sBits, int nblk, int nb2) {
    __shared__ unsigned stage[4096];
    __shared__ unsigned short bkid[4096];
    __shared__ int hist[512], sd[256], cursor[512], rebase[512];
    int tid = threadIdx.x;
    int base = blockIdx.x * 4096;
    hist[tid] = 0; hist[tid + 256] = 0;
    __syncthreads();

    unsigned ent[16];
    int bk[16];
    int lowmask = (1 << bshift) - 1;
    int dshift = sBits + 1;
#pragma unroll
    for (int r = 0; r < 16; r++) {
        int i = base + tid + r * 256;
        if (i < E) {
            int s = ei[i];
            int d = ei[E + i];
            int t = ety[i];
            ent[r] = ((unsigned)(d & lowmask) << dshift) | ((unsigned)t << sBits) | (unsigned)s;
            bk[r] = d >> bshift;
            atomicAdd(&hist[bk[r]], 1);
        } else bk[r] = -1;
    }
    __syncthreads();

    int v0 = hist[2 * tid], v1 = hist[2 * tid + 1];
    int sum2 = v0 + v1;
    sd[tid] = sum2; __syncthreads();
    for (int off = 1; off < 256; off <<= 1) {
        int x = (tid >= off) ? sd[tid - off] : 0;
        __syncthreads();
        sd[tid] += x;
        __syncthreads();
    }
    int exclPair = sd[tid] - sum2;
    __syncthreads();
    cursor[2 * tid] = exclPair;
    cursor[2 * tid + 1] = exclPair + v0;
    int b0 = 2 * tid, b1 = 2 * tid + 1;
    rebase[b0] = (b0 < nb2 && v0 > 0) ? (cntScan[b0 * nblk + blockIdx.x] - v0) - exclPair : 0;
    rebase[b1] = (b1 < nb2 && v1 > 0) ? (cntScan[b1 * nblk + blockIdx.x] - v1) - (exclPair + v0) : 0;
    __syncthreads();

#pragma unroll
    for (int r = 0; r < 16; r++) {
        if (bk[r] >= 0) {
            int p = atomicAdd(&cursor[bk[r]], 1);
            stage[p] = ent[r];
            bkid[p] = (unsigned short)bk[r];
        }
    }
    __syncthreads();

    int cnt = E - base; if (cnt > 4096) cnt = 4096;
    for (int i = tid; i < cnt; i += 256)
        binned[rebase[bkid[i]] + i] = stage[i];
}

__global__ __launch_bounds__(256) void passC_k(const unsigned* __restrict__ binned,
                                               const int* __restrict__ cntScan,
                                               int nblk, int* __restrict__ rowptr,
                                               unsigned* __restrict__ sorted,
                                               int N, int E, int bshift, int sBits,
                                               int nb2) {
    __shared__ int hist[512], cursor[512], sd[256];
    int tid = threadIdx.x;
    int b = blockIdx.x;
    int s = (b == 0) ? 0 : cntScan[b * nblk - 1];
    int e = cntScan[(b + 1) * nblk - 1];
    int nodeBase = b << bshift;
    int dshift = sBits + 1;

    hist[tid] = 0; hist[tid + 256] = 0;
    __syncthreads();
    for (int i = s + tid; i < e; i += 256)
        atomicAdd(&hist[(int)(binned[i] >> dshift)], 1);
    __syncthreads();

    int v0 = hist[2 * tid], v1 = hist[2 * tid + 1];
    int sum2 = v0 + v1;
    sd[tid] = sum2; __syncthreads();
    for (int off = 1; off < 256; off <<= 1) {
        int x = (tid >= off) ? sd[tid - off] : 0;
        __syncthreads();
        sd[tid] += x;
        __syncthreads();
    }
    int exclPair = sd[tid] - sum2;
    __syncthreads();
    cursor[2 * tid] = exclPair;
    cursor[2 * tid + 1] = exclPair + v0;
    int n0 = nodeBase + 2 * tid, n1 = nodeBase + 2 * tid + 1;
    if (n0 < N) rowptr[n0] = s + exclPair;
    if (n1 < N) rowptr[n1] = s + exclPair + v0;
    __syncthreads();

    for (int i = s + tid; i < e; i += 256) {
        unsigned en = binned[i];
        int ln = (int)(en >> dshift);
        int p = atomicAdd(&cursor[ln], 1);
        sorted[s + p] = en;
    }
    if (b == nb2 - 1 && tid == 0) rowptr[N] = E;
}

// prep: copy x->packed fp16 pairs in P (+sentinel -inf rows), init pool buffers
__global__ void prep_k(const float* __restrict__ x, unsigned* __restrict__ P,
                       unsigned* __restrict__ Q, int N,
                       unsigned* __restrict__ maxb, float* __restrict__ sumb, int G64) {
    int i = blockIdx.x * 256 + threadIdx.x;
    int tot = N * 16;
    if (i < tot) {
        float2 v = ((const float2*)x)[i];
        f16x2 hv;
        hv.x = (_Float16)v.x;
        hv.y = (_Float16)v.y;
        P[i] = *(unsigned*)&hv;
    }
    if (i < 16) {
        P[tot + i] = 0xFC00FC00u;   // (-inf, -inf) fp16
        Q[tot + i] = 0xFC00FC00u;
    }
    if (i < G64) { maxb[i] = 0x007FFFFFu; sumb[i] = 0.f; }
}

// ---------- layer A: 16 ch-lanes x 2 edge slots, packed fp16 h ----------
__global__ __launch_bounds__(256) void layerA_k(
    const unsigned* __restrict__ hin, const int* __restrict__ rowptr,
    const unsigned* __restrict__ sorted, const float* __restrict__ emb,
    const float* __restrict__ W1, const float* __restrict__ b1,
    float* __restrict__ tout, float* __restrict__ partial, int Nn, int sBits,
    unsigned sentw)
{
    float2* tout2 = (float2*)tout;
    int tid = threadIdx.x;
    int gl = tid & 31;
    int c = gl & 15;            // channel-pair index
    int slot = gl >> 4;         // edge slot / k-half
    int grp = tid >> 5;
    unsigned smask = (1u << sBits) - 1u;

    float2 w1c[16];
#pragma unroll
    for (int kk = 0; kk < 16; kk++)
        w1c[kk] = *(const float2*)&W1[(16 * slot + kk) * 32 + 2 * c];
    float2 b1p = *(const float2*)&b1[2 * c];
    f16x2 e0p, e1p, zero2;
    e0p.x = (_Float16)emb[2 * c];       e0p.y = (_Float16)emb[2 * c + 1];
    e1p.x = (_Float16)emb[32 + 2 * c];  e1p.y = (_Float16)emb[32 + 2 * c + 1];
    zero2.x = (_Float16)0.f;            zero2.y = (_Float16)0.f;

    __shared__ float zl[8][32];
    __shared__ float ls[8][32], lq[8][32];

    float2 bsum = {0.f, 0.f}, bsq = {0.f, 0.f};

    int gid0 = (blockIdx.x * 256 + tid) >> 5;
    int nG = (gridDim.x * 256) >> 5;

    for (int n = gid0; n < Nn; n += nG) {
        int es = rowptr[n], ee = rowptr[n + 1];
        float accx = 0.f, accy = 0.f;
        for (int e0 = es; e0 < ee; e0 += 32) {
            int idx = e0 + gl;
            unsigned pv = (idx < ee) ? sorted[idx] : sentw;
#pragma unroll
            for (int kk = 0; kk < 16; kk++) {
                unsigned p = (unsigned)__shfl((int)pv, kk, 16);
                unsigned s = p & smask;
                unsigned w = hin[s * 16u + (unsigned)c];
                f16x2 h2 = *reinterpret_cast<const f16x2*>(&w);
                f16x2 ev = (((p >> sBits) & 1u) != 0u) ? e1p : e0p;
                f16x2 rl = __builtin_elementwise_max(h2 + ev, zero2);
                accx += (float)rl.x;
                accy += (float)rl.y;
            }
        }
        accx += __shfl_xor(accx, 16);
        accy += __shfl_xor(accy, 16);
        unsigned wn = hin[(unsigned)n * 16u + (unsigned)c];
        f16x2 fn = *reinterpret_cast<const f16x2*>(&wn);
        accx += (float)fn.x;
        accy += (float)fn.y;

        if (slot == 0) { zl[grp][2 * c] = accx; zl[grp][2 * c + 1] = accy; }
        float tx = 0.f, ty = 0.f;
#pragma unroll
        for (int kk = 0; kk < 16; kk++) {
            float zk = zl[grp][16 * slot + kk];
            tx = fmaf(zk, w1c[kk].x, tx);
            ty = fmaf(zk, w1c[kk].y, ty);
        }
        tx += __shfl_xor(tx, 16);
        ty += __shfl_xor(ty, 16);
        tx += b1p.x; ty += b1p.y;
        if (slot == 0) { float2 tp; tp.x = tx; tp.y = ty; tout2[(unsigned)n * 16u + (unsigned)c] = tp; }
        bsum.x += tx; bsum.y += ty;
        bsq.x = fmaf(tx, tx, bsq.x);
        bsq.y = fmaf(ty, ty, bsq.y);
    }

    if (slot == 0) {
        ls[grp][2 * c] = bsum.x; ls[grp][2 * c + 1] = bsum.y;
        lq[grp][2 * c] = bsq.x;  lq[grp][2 * c + 1] = bsq.y;
    }
    __syncthreads();
    if (tid < 32) {
        float s = 0.f, q = 0.f;
#pragma unroll
        for (int r = 0; r < 8; r++) { s += ls[r][tid]; q += lq[r][tid]; }
        partial[blockIdx.x * 64 + tid] = s;
        partial[blockIdx.x * 64 + 32 + tid] = q;
    }
}

// ---------- BN stage 1: 2048 partial rows -> partial2[64][64] ----------
__global__ __launch_bounds__(256) void bnred1_k(const float* __restrict__ partial,
                                                float* __restrict__ partial2) {
    __shared__ float sd[4][64];
    int tid = threadIdx.x;
    int c = tid & 63, q = tid >> 6;
    int rowBase = blockIdx.x * 32 + q * 8;
    float s = 0.f;
#pragma unroll
    for (int r = 0; r < 8; r++) s += partial[(rowBase + r) * 64 + c];
    sd[q][c] = s;
    __syncthreads();
    if (q == 0) partial2[blockIdx.x * 64 + c] = sd[0][c] + sd[1][c] + sd[2][c] + sd[3][c];
}

// shared prologue: every block reduces partial2 -> LDS bn_ac (deterministic, identical)
__device__ __forceinline__ void bn_prologue(const float* __restrict__ partial2,
                                            const float* __restrict__ gamma,
                                            const float* __restrict__ beta,
                                            float invN, float* bnac /*LDS[64]*/,
                                            float (*sd4)[64] /*LDS[4][64]*/) {
    int tid = threadIdx.x;
    int c = tid & 63, q = tid >> 6;
    float s = 0.f;
#pragma unroll
    for (int r = 0; r < 16; r++) s += partial2[(q * 16 + r) * 64 + c];
    sd4[q][c] = s;
    __syncthreads();
    if (tid < 32) {
        float mu  = (sd4[0][tid] + sd4[1][tid] + sd4[2][tid] + sd4[3][tid]) * invN;
        float sq  = (sd4[0][tid + 32] + sd4[1][tid + 32] + sd4[2][tid + 32] + sd4[3][tid + 32]) * invN;
        float var = sq - mu * mu;
        float a = gamma[tid] * rsqrtf(var + 1e-5f);
        bnac[tid] = a;
        bnac[32 + tid] = beta[tid] - a * mu;
    }
    __syncthreads();
}

// ---------- layer B (1-4): bn-prologue + relu(bn(t)) @ W2 + b2, +relu, packed fp16 out ----------
__global__ __launch_bounds__(256) void layerB32_k(
    const float* __restrict__ tin, const float* __restrict__ partial2,
    const float* __restrict__ gamma, const float* __restrict__ beta, float invN,
    const float* __restrict__ W2, const float* __restrict__ b2,
    unsigned* __restrict__ hout, int Nn)
{
    __shared__ float bnac[64];
    __shared__ float sd4[4][64];
    bn_prologue(partial2, gamma, beta, invN, bnac, sd4);

    int tid = threadIdx.x;
    int j = tid & 31, grp = tid >> 5;
    float a = bnac[j], c = bnac[32 + j];
    float wc[32];
#pragma unroll
    for (int k = 0; k < 32; k++) wc[k] = W2[k * 32 + j];
    float bj = b2[j];
    for (int n = blockIdx.x * 8 + grp; n < Nn; n += gridDim.x * 8) {
        float t = tin[n * 32 + j];
        float u = fmaxf(fmaf(a, t, c), 0.f);
        float o = bj;
#pragma unroll
        for (int k = 0; k < 32; k++) o = fmaf(__shfl(u, k, 32), wc[k], o);
        _Float16 hv = (_Float16)fmaxf(o, 0.f);
        unsigned hb = (unsigned)*reinterpret_cast<unsigned short*>(&hv);
        unsigned nb = (unsigned)__shfl_xor((int)hb, 1, 32);
        if ((j & 1) == 0) hout[(unsigned)n * 16u + (unsigned)(j >> 1)] = hb | (nb << 16);
    }
}

// ---------- layer B5 + pooling fused (+bn prologue) ----------
__global__ __launch_bounds__(256) void layerB64pool_k(
    const float* __restrict__ tin, const float* __restrict__ partial2,
    const float* __restrict__ gamma, const float* __restrict__ beta, float invN,
    const float* __restrict__ W2, const float* __restrict__ b2,
    const int* __restrict__ batch,
    unsigned* __restrict__ maxb, float* __restrict__ sumb, int Nn)
{
    __shared__ float bnac[64];
    __shared__ float sd4[4][64];
    bn_prologue(partial2, gamma, beta, invN, bnac, sd4);

    int tid = threadIdx.x;
    int j = tid & 31, grp = tid >> 5;
    float a = bnac[j], c = bnac[32 + j];
    float wlo[32], whi[32];
#pragma unroll
    for (int k = 0; k < 32; k++) { wlo[k] = W2[k * 64 + j]; whi[k] = W2[k * 64 + 32 + j]; }
    float blo = b2[j], bhi = b2[32 + j];

    int n0 = (blockIdx.x * 8 + grp) * 64;
    if (n0 >= Nn) return;
    int nend = n0 + 64; if (nend > Nn) nend = Nn;

    int curg = -1;
    float mxl = 0.f, mxh = 0.f, sml = 0.f, smh = 0.f;
    for (int n = n0; n < nend; n++) {
        float t = tin[n * 32 + j];
        float u = fmaxf(fmaf(a, t, c), 0.f);
        float olo = blo, ohi = bhi;
#pragma unroll
        for (int k = 0; k < 32; k++) {
            float uk = __shfl(u, k, 32);
            olo = fmaf(uk, wlo[k], olo);
            ohi = fmaf(uk, whi[k], ohi);
        }
        int gn = batch[n];
        if (gn != curg) {
            if (curg >= 0) {
                atomicMax(&maxb[curg * 64 + j], encf(mxl));
                atomicMax(&maxb[curg * 64 + 32 + j], encf(mxh));
                atomicAdd(&sumb[curg * 64 + j], sml);
                atomicAdd(&sumb[curg * 64 + 32 + j], smh);
            }
            curg = gn; mxl = olo; mxh = ohi; sml = olo; smh = ohi;
        } else {
            mxl = fmaxf(mxl, olo); mxh = fmaxf(mxh, ohi);
            sml += olo; smh += ohi;
        }
    }
    if (curg >= 0) {
        atomicMax(&maxb[curg * 64 + j], encf(mxl));
        atomicMax(&maxb[curg * 64 + 32 + j], encf(mxh));
        atomicAdd(&sumb[curg * 64 + j], sml);
        atomicAdd(&sumb[curg * 64 + 32 + j], smh);
    }
}

__global__ void final_k(const unsigned* __restrict__ maxb, const float* __restrict__ sumb,
                        const int* __restrict__ batch, int Nn, float* __restrict__ out)
{
    int g = blockIdx.x, tid = threadIdx.x;
    int a = 0, b = Nn;
    while (a < b) { int m = (a + b) >> 1; if (batch[m] < g) a = m + 1; else b = m; }
    int lo0 = a;
    a = 0; b = Nn;
    while (a < b) { int m = (a + b) >> 1; if (batch[m] < g + 1) a = m + 1; else b = m; }
    int hi0 = a;
    float inv = 1.f / fmaxf((float)(hi0 - lo0), 1.f);
    if (tid < 64) out[g * 128 + tid] = decf(maxb[g * 64 + tid]);
    else          out[g * 128 + tid] = sumb[g * 64 + (tid - 64)] * inv;
}

extern "C" void kernel_launch(void* const* d_in, const int* in_sizes, int n_in,
                              void* d_out, int out_size, void* d_ws, size_t ws_size,
                              hipStream_t stream) {
    const float* x    = (const float*)d_in[0];
    const int*   ei   = (const int*)d_in[1];
    const int*   ety  = (const int*)d_in[2];
    const int*   batch= (const int*)d_in[3];
    const float* emb  = (const float*)d_in[4];
    const float* W1s  = (const float*)d_in[5];
    const float* b1s  = (const float*)d_in[6];
    const float* g1s  = (const float*)d_in[7];
    const float* be1s = (const float*)d_in[8];
    const float* W2s  = (const float*)d_in[9];
    const float* b2s  = (const float*)d_in[10];
    const float* w15  = (const float*)d_in[11];
    const float* b15  = (const float*)d_in[12];
    const float* g5   = (const float*)d_in[13];
    const float* be5  = (const float*)d_in[14];
    const float* w25  = (const float*)d_in[15];
    const float* b25  = (const float*)d_in[16];

    int N = in_sizes[0] / 32;
    int E = in_sizes[1] / 2;
    int G = out_size / 128;

    int sBits = 1; while ((1 << sBits) < N + 1) sBits++;            // 18
    int bshift = 0; while (((N - 1) >> bshift) >= 512) bshift++;    // 9
    int nb2 = ((N - 1) >> bshift) + 1;                              // 391
    int nblkE = (E + 4095) / 4096;                                  // 977

    char* wsb = (char*)d_ws;
    size_t o = 0;
    size_t hPkBytes = (size_t)(N + 1) * 16 * 4;
    size_t tbBytes = (size_t)N * 32 * 4;
    size_t binBytes = (size_t)E * 4;
    size_t rtb = tbBytes > binBytes ? tbBytes : binBytes;
    unsigned* P      = (unsigned*)(wsb + o); o += hPkBytes;
    unsigned* Q      = (unsigned*)(wsb + o); o += hPkBytes;
    float*    tb     = (float*)(wsb + o);
    unsigned* binned = (unsigned*)(wsb + o);        // alias: dead before layerA L0
    o += rtb;
    int*      rowptr = (int*)(wsb + o);   o += ((size_t)N + 2) * 4;
    unsigned* sorted = (unsigned*)(wsb + o); o += (size_t)E * 4;
    int*      chunkTot = (int*)(wsb + o); o += 1024;
    float*    partial  = (float*)(wsb + o); o += (size_t)NBLKA * 64 * 4;
    float*    partial2 = (float*)(wsb + o); o += 64 * 64 * 4;
    unsigned* maxb     = (unsigned*)(wsb + o); o += (size_t)G * 64 * 4;
    float*    sumb     = (float*)(wsb + o); o += (size_t)G * 64 * 4;
    int*      cntMat   = (int*)(wsb + o); o += (size_t)nb2 * nblkE * 4;

    // ---- CSR build ----
    passA_k<<<nblkE, 256, 0, stream>>>(ei + E, E, cntMat, bshift, nblkE, nb2);
    int total2 = nb2 * nblkE;
    int nchunk2 = (total2 + 2047) / 2048;
    scanA_k<<<nchunk2, 256, 0, stream>>>(cntMat, total2, chunkTot);
    scanC3_k<<<nchunk2, 256, 0, stream>>>(cntMat, total2, chunkTot, nchunk2);
    passB_k<<<nblkE, 256, 0, stream>>>(ei, ety, E, cntMat, binned, bshift, sBits, nblkE, nb2);
    passC_k<<<nb2, 256, 0, stream>>>(binned, cntMat, nblkE, rowptr, sorted, N, E, bshift, sBits, nb2);
    prep_k<<<(N * 16 + 255) / 256, 256, 0, stream>>>(x, P, Q, N, maxb, sumb, G * 64);

    unsigned sentw = (unsigned)N;
    float invN = 1.f / (float)N;

    // ---- 5 GINE layers (ping-pong P<->Q; bn_ac computed in layerB prologue) ----
    unsigned* inb = P;
    unsigned* outb = Q;
    for (int L = 0; L < 5; ++L) {
        const float* W1 = (L < 4) ? W1s + L * 1024 : w15;
        const float* b1 = (L < 4) ? b1s + L * 32  : b15;
        const float* ga = (L < 4) ? g1s + L * 32  : g5;
        const float* be = (L < 4) ? be1s + L * 32 : be5;
        const float* W2 = (L < 4) ? W2s + L * 1024 : w25;
        const float* b2 = (L < 4) ? b2s + L * 32  : b25;

        layerA_k<<<NBLKA, 256, 0, stream>>>(inb, rowptr, sorted, emb, W1, b1, tb, partial, N, sBits, sentw);
        bnred1_k<<<64, 256, 0, stream>>>(partial, partial2);
        if (L < 4) {
            layerB32_k<<<1024, 256, 0, stream>>>(tb, partial2, ga, be, invN, W2, b2, outb, N);
            unsigned* tmp = inb; inb = outb; outb = tmp;
        } else {
            layerB64pool_k<<<(N + 511) / 512, 256, 0, stream>>>(tb, partial2, ga, be, invN, W2, b2, batch, maxb, sumb, N);
        }
    }

    // ---- output ----
    final_k<<<G, 128, 0, stream>>>(maxb, sumb, batch, N, (float*)d_out);
}

// Round 14
// 576.633 us; speedup vs baseline: 4.1431x; 1.1638x over previous
//
#include <hip/hip_runtime.h>
#include <hip/hip_fp16.h>

#define NBLKA 2048

typedef _Float16 f16x2 __attribute__((ext_vector_type(2)));

__device__ __forceinline__ unsigned encf(float x) {
    unsigned u = __float_as_uint(x);
    return (u & 0x80000000u) ? ~u : (u | 0x80000000u);
}
__device__ __forceinline__ float decf(unsigned u) {
    u = (u & 0x80000000u) ? (u & 0x7FFFFFFFu) : ~u;
    return __uint_as_float(u);
}
__device__ __forceinline__ unsigned packf16(float x, float y) {
    f16x2 hv;
    hv.x = (_Float16)x;
    hv.y = (_Float16)y;
    return *reinterpret_cast<unsigned*>(&hv);
}
__device__ __forceinline__ float2 unpackf16(unsigned w) {
    f16x2 hv = *reinterpret_cast<const f16x2*>(&w);
    float2 f;
    f.x = (float)hv.x;
    f.y = (float)hv.y;
    return f;
}

// ============ CSR build: 512-node buckets, deterministic matrix scan ============

__global__ __launch_bounds__(256) void passA_k(const int* __restrict__ dst, int E,
                                               int* __restrict__ cntMat, int bshift,
                                               int nblk, int nb2) {
    __shared__ int hist[512];
    hist[threadIdx.x] = 0; hist[threadIdx.x + 256] = 0;
    __syncthreads();
    int base = blockIdx.x * 4096;
#pragma unroll
    for (int r = 0; r < 16; r++) {
        int i = base + threadIdx.x + r * 256;
        if (i < E) atomicAdd(&hist[dst[i] >> bshift], 1);
    }
    __syncthreads();
    for (int bk = threadIdx.x; bk < nb2; bk += 256)
        cntMat[bk * nblk + blockIdx.x] = hist[bk];
}

__global__ void scanA_k(int* __restrict__ data, int total, int* __restrict__ chunkTot) {
    __shared__ int sd[256];
    int tid = threadIdx.x;
    int base = blockIdx.x * 2048 + tid * 8;
    int v[8]; int s = 0;
#pragma unroll
    for (int r = 0; r < 8; r++) {
        int idx = base + r;
        int x = (idx < total) ? data[idx] : 0;
        s += x; v[r] = s;
    }
    sd[tid] = s; __syncthreads();
    for (int off = 1; off < 256; off <<= 1) {
        int x = (tid >= off) ? sd[tid - off] : 0;
        __syncthreads();
        sd[tid] += x;
        __syncthreads();
    }
    int prev = (tid > 0) ? sd[tid - 1] : 0;
#pragma unroll
    for (int r = 0; r < 8; r++) {
        int idx = base + r;
        if (idx < total) data[idx] = v[r] + prev;
    }
    if (tid == 255) chunkTot[blockIdx.x] = sd[255];
}

// scanC3: each block re-scans chunkTot in LDS (nchunk<=256) and applies its offset
__global__ void scanC3_k(int* __restrict__ data, int total,
                         const int* __restrict__ chunkTot, int nchunk) {
    __shared__ int sd[256];
    int tid = threadIdx.x;
    int v = (tid < nchunk) ? chunkTot[tid] : 0;
    sd[tid] = v; __syncthreads();
    for (int off = 1; off < 256; off <<= 1) {
        int x = (tid >= off) ? sd[tid - off] : 0;
        __syncthreads();
        sd[tid] += x;
        __syncthreads();
    }
    int boff = (blockIdx.x > 0) ? sd[blockIdx.x - 1] : 0;
    int base = blockIdx.x * 2048 + tid * 8;
#pragma unroll
    for (int r = 0; r < 8; r++) {
        int idx = base + r;
        if (idx < total) data[idx] += boff;
    }
}

__global__ __launch_bounds__(256) void passB_k(const int* __restrict__ ei,
                                               const int* __restrict__ ety, int E,
                                               const int* __restrict__ cntScan,
                                               unsigned* __restrict__ binned,
                                               int bshift, int sBits, int nblk, int nb2) {
    __shared__ unsigned stage[4096];
    __shared__ unsigned short bkid[4096];
    __shared__ int hist[512], sd[256], cursor[512], rebase[512];
    int tid = threadIdx.x;
    int base = blockIdx.x * 4096;
    hist[tid] = 0; hist[tid + 256] = 0;
    __syncthreads();

    unsigned ent[16];
    int bk[16];
    int lowmask = (1 << bshift) - 1;
    int dshift = sBits + 1;
#pragma unroll
    for (int r = 0; r < 16; r++) {
        int i = base + tid + r * 256;
        if (i < E) {
            int s = ei[i];
            int d = ei[E + i];
            int t = ety[i];
            ent[r] = ((unsigned)(d & lowmask) << dshift) | ((unsigned)t << sBits) | (unsigned)s;
            bk[r] = d >> bshift;
            atomicAdd(&hist[bk[r]], 1);
        } else bk[r] = -1;
    }
    __syncthreads();

    int v0 = hist[2 * tid], v1 = hist[2 * tid + 1];
    int sum2 = v0 + v1;
    sd[tid] = sum2; __syncthreads();
    for (int off = 1; off < 256; off <<= 1) {
        int x = (tid >= off) ? sd[tid - off] : 0;
        __syncthreads();
        sd[tid] += x;
        __syncthreads();
    }
    int exclPair = sd[tid] - sum2;
    __syncthreads();
    cursor[2 * tid] = exclPair;
    cursor[2 * tid + 1] = exclPair + v0;
    int b0 = 2 * tid, b1 = 2 * tid + 1;
    rebase[b0] = (b0 < nb2 && v0 > 0) ? (cntScan[b0 * nblk + blockIdx.x] - v0) - exclPair : 0;
    rebase[b1] = (b1 < nb2 && v1 > 0) ? (cntScan[b1 * nblk + blockIdx.x] - v1) - (exclPair + v0) : 0;
    __syncthreads();

#pragma unroll
    for (int r = 0; r < 16; r++) {
        if (bk[r] >= 0) {
            int p = atomicAdd(&cursor[bk[r]], 1);
            stage[p] = ent[r];
            bkid[p] = (unsigned short)bk[r];
        }
    }
    __syncthreads();

    int cnt = E - base; if (cnt > 4096) cnt = 4096;
    for (int i = tid; i < cnt; i += 256)
        binned[rebase[bkid[i]] + i] = stage[i];
}

__global__ __launch_bounds__(256) void passC_k(const unsigned* __restrict__ binned,
                                               const int* __restrict__ cntScan,
                                               int nblk, int* __restrict__ rowptr,
                                               unsigned* __restrict__ sorted,
                                               int N, int E, int bshift, int sBits,
                                               int nb2) {
    __shared__ int hist[512], cursor[512], sd[256];
    int tid = threadIdx.x;
    int b = blockIdx.x;
    int s = (b == 0) ? 0 : cntScan[b * nblk - 1];
    int e = cntScan[(b + 1) * nblk - 1];
    int nodeBase = b << bshift;
    int dshift = sBits + 1;

    hist[tid] = 0; hist[tid + 256] = 0;
    __syncthreads();
    for (int i = s + tid; i < e; i += 256)
        atomicAdd(&hist[(int)(binned[i] >> dshift)], 1);
    __syncthreads();

    int v0 = hist[2 * tid], v1 = hist[2 * tid + 1];
    int sum2 = v0 + v1;
    sd[tid] = sum2; __syncthreads();
    for (int off = 1; off < 256; off <<= 1) {
        int x = (tid >= off) ? sd[tid - off] : 0;
        __syncthreads();
        sd[tid] += x;
        __syncthreads();
    }
    int exclPair = sd[tid] - sum2;
    __syncthreads();
    cursor[2 * tid] = exclPair;
    cursor[2 * tid + 1] = exclPair + v0;
    int n0 = nodeBase + 2 * tid, n1 = nodeBase + 2 * tid + 1;
    if (n0 < N) rowptr[n0] = s + exclPair;
    if (n1 < N) rowptr[n1] = s + exclPair + v0;
    __syncthreads();

    for (int i = s + tid; i < e; i += 256) {
        unsigned en = binned[i];
        int ln = (int)(en >> dshift);
        int p = atomicAdd(&cursor[ln], 1);
        sorted[s + p] = en;
    }
    if (b == nb2 - 1 && tid == 0) rowptr[N] = E;
}

// prep: copy x->packed fp16 pairs in P (+sentinel -inf rows), init pool buffers
__global__ void prep_k(const float* __restrict__ x, unsigned* __restrict__ P,
                       unsigned* __restrict__ Q, int N,
                       unsigned* __restrict__ maxb, float* __restrict__ sumb, int G64) {
    int i = blockIdx.x * 256 + threadIdx.x;
    int tot = N * 16;
    if (i < tot) {
        float2 v = ((const float2*)x)[i];
        P[i] = packf16(v.x, v.y);
    }
    if (i < 16) {
        P[tot + i] = 0xFC00FC00u;   // (-inf, -inf) fp16
        Q[tot + i] = 0xFC00FC00u;
    }
    if (i < G64) { maxb[i] = 0x007FFFFFu; sumb[i] = 0.f; }
}

// ---------- layer A: 16 ch-lanes x 2 edge slots, packed fp16 h, fp16 t out ----------
__global__ __launch_bounds__(256) void layerA_k(
    const unsigned* __restrict__ hin, const int* __restrict__ rowptr,
    const unsigned* __restrict__ sorted, const float* __restrict__ emb,
    const float* __restrict__ W1, const float* __restrict__ b1,
    unsigned* __restrict__ tout, float* __restrict__ partial, int Nn, int sBits,
    unsigned sentw)
{
    int tid = threadIdx.x;
    int gl = tid & 31;
    int c = gl & 15;            // channel-pair index
    int slot = gl >> 4;         // edge slot / k-half
    int grp = tid >> 5;
    unsigned smask = (1u << sBits) - 1u;

    float2 w1c[16];
#pragma unroll
    for (int kk = 0; kk < 16; kk++)
        w1c[kk] = *(const float2*)&W1[(16 * slot + kk) * 32 + 2 * c];
    float2 b1p = *(const float2*)&b1[2 * c];
    f16x2 e0p, e1p, zero2;
    e0p.x = (_Float16)emb[2 * c];       e0p.y = (_Float16)emb[2 * c + 1];
    e1p.x = (_Float16)emb[32 + 2 * c];  e1p.y = (_Float16)emb[32 + 2 * c + 1];
    zero2.x = (_Float16)0.f;            zero2.y = (_Float16)0.f;

    __shared__ float zl[8][32];
    __shared__ float ls[8][32], lq[8][32];

    float2 bsum = {0.f, 0.f}, bsq = {0.f, 0.f};

    int gid0 = (blockIdx.x * 256 + tid) >> 5;
    int nG = (gridDim.x * 256) >> 5;

    for (int n = gid0; n < Nn; n += nG) {
        int es = rowptr[n], ee = rowptr[n + 1];
        float accx = 0.f, accy = 0.f;
        for (int e0 = es; e0 < ee; e0 += 32) {
            int idx = e0 + gl;
            unsigned pv = (idx < ee) ? sorted[idx] : sentw;
#pragma unroll
            for (int kk = 0; kk < 16; kk++) {
                unsigned p = (unsigned)__shfl((int)pv, kk, 16);
                unsigned s = p & smask;
                unsigned w = hin[s * 16u + (unsigned)c];
                f16x2 h2 = *reinterpret_cast<const f16x2*>(&w);
                f16x2 ev = (((p >> sBits) & 1u) != 0u) ? e1p : e0p;
                f16x2 rl = __builtin_elementwise_max(h2 + ev, zero2);
                accx += (float)rl.x;
                accy += (float)rl.y;
            }
        }
        accx += __shfl_xor(accx, 16);
        accy += __shfl_xor(accy, 16);
        unsigned wn = hin[(unsigned)n * 16u + (unsigned)c];
        f16x2 fn = *reinterpret_cast<const f16x2*>(&wn);
        accx += (float)fn.x;
        accy += (float)fn.y;

        if (slot == 0) { zl[grp][2 * c] = accx; zl[grp][2 * c + 1] = accy; }
        float tx = 0.f, ty = 0.f;
#pragma unroll
        for (int kk = 0; kk < 16; kk++) {
            float zk = zl[grp][16 * slot + kk];
            tx = fmaf(zk, w1c[kk].x, tx);
            ty = fmaf(zk, w1c[kk].y, ty);
        }
        tx += __shfl_xor(tx, 16);
        ty += __shfl_xor(ty, 16);
        tx += b1p.x; ty += b1p.y;
        if (slot == 0) tout[(unsigned)n * 16u + (unsigned)c] = packf16(tx, ty);
        bsum.x += tx; bsum.y += ty;
        bsq.x = fmaf(tx, tx, bsq.x);
        bsq.y = fmaf(ty, ty, bsq.y);
    }

    if (slot == 0) {
        ls[grp][2 * c] = bsum.x; ls[grp][2 * c + 1] = bsum.y;
        lq[grp][2 * c] = bsq.x;  lq[grp][2 * c + 1] = bsq.y;
    }
    __syncthreads();
    if (tid < 32) {
        float s = 0.f, q = 0.f;
#pragma unroll
        for (int r = 0; r < 8; r++) { s += ls[r][tid]; q += lq[r][tid]; }
        partial[blockIdx.x * 64 + tid] = s;
        partial[blockIdx.x * 64 + 32 + tid] = q;
    }
}

// ---------- BN stage 1: 2048 partial rows -> partial2[64][64] ----------
__global__ __launch_bounds__(256) void bnred1_k(const float* __restrict__ partial,
                                                float* __restrict__ partial2) {
    __shared__ float sd[4][64];
    int tid = threadIdx.x;
    int c = tid & 63, q = tid >> 6;
    int rowBase = blockIdx.x * 32 + q * 8;
    float s = 0.f;
#pragma unroll
    for (int r = 0; r < 8; r++) s += partial[(rowBase + r) * 64 + c];
    sd[q][c] = s;
    __syncthreads();
    if (q == 0) partial2[blockIdx.x * 64 + c] = sd[0][c] + sd[1][c] + sd[2][c] + sd[3][c];
}

// shared prologue: every block reduces partial2 -> LDS bn_ac (deterministic, identical)
__device__ __forceinline__ void bn_prologue(const float* __restrict__ partial2,
                                            const float* __restrict__ gamma,
                                            const float* __restrict__ beta,
                                            float invN, float* bnac /*LDS[64]*/,
                                            float (*sd4)[64] /*LDS[4][64]*/) {
    int tid = threadIdx.x;
    int c = tid & 63, q = tid >> 6;
    float s = 0.f;
#pragma unroll
    for (int r = 0; r < 16; r++) s += partial2[(q * 16 + r) * 64 + c];
    sd4[q][c] = s;
    __syncthreads();
    if (tid < 32) {
        float mu  = (sd4[0][tid] + sd4[1][tid] + sd4[2][tid] + sd4[3][tid]) * invN;
        float sq  = (sd4[0][tid + 32] + sd4[1][tid + 32] + sd4[2][tid + 32] + sd4[3][tid + 32]) * invN;
        float var = sq - mu * mu;
        float a = gamma[tid] * rsqrtf(var + 1e-5f);
        bnac[tid] = a;
        bnac[32 + tid] = beta[tid] - a * mu;
    }
    __syncthreads();
}

// ---------- layer B (1-4): bn-prologue + relu(bn(t)) @ W2 + b2, +relu ----------
// k-half split: 16 ch-pair lanes x 2 k-half slots per 32-group, fp16 t in, fp16 h out
__global__ __launch_bounds__(256) void layerB32_k(
    const unsigned* __restrict__ tin, const float* __restrict__ partial2,
    const float* __restrict__ gamma, const float* __restrict__ beta, float invN,
    const float* __restrict__ W2, const float* __restrict__ b2,
    unsigned* __restrict__ hout, int Nn)
{
    __shared__ float bnac[64];
    __shared__ float sd4[4][64];
    bn_prologue(partial2, gamma, beta, invN, bnac, sd4);

    int tid = threadIdx.x;
    int gl = tid & 31;
    int c = gl & 15;            // channel-pair index
    int slot = gl >> 4;         // k-half
    int grp = tid >> 5;

    float2 w2c[16];
#pragma unroll
    for (int kk = 0; kk < 16; kk++)
        w2c[kk] = *(const float2*)&W2[(16 * slot + kk) * 32 + 2 * c];
    float2 a2 = *(const float2*)&bnac[2 * c];
    float2 c2 = *(const float2*)&bnac[32 + 2 * c];
    float2 b2p = *(const float2*)&b2[2 * c];

    __shared__ float zl[8][32];

    int gid0 = (blockIdx.x * 256 + tid) >> 5;
    int nG = (gridDim.x * 256) >> 5;

    for (int n = gid0; n < Nn; n += nG) {
        float2 t2 = unpackf16(tin[(unsigned)n * 16u + (unsigned)c]);
        float ux = fmaxf(fmaf(a2.x, t2.x, c2.x), 0.f);
        float uy = fmaxf(fmaf(a2.y, t2.y, c2.y), 0.f);
        if (slot == 0) { zl[grp][2 * c] = ux; zl[grp][2 * c + 1] = uy; }
        float ox = 0.f, oy = 0.f;
#pragma unroll
        for (int kk = 0; kk < 16; kk++) {
            float uk = zl[grp][16 * slot + kk];
            ox = fmaf(uk, w2c[kk].x, ox);
            oy = fmaf(uk, w2c[kk].y, oy);
        }
        ox += __shfl_xor(ox, 16);
        oy += __shfl_xor(oy, 16);
        ox = fmaxf(ox + b2p.x, 0.f);
        oy = fmaxf(oy + b2p.y, 0.f);
        if (slot == 0) hout[(unsigned)n * 16u + (unsigned)c] = packf16(ox, oy);
    }
}

// ---------- layer B5 + pooling fused (+bn prologue), fp16 t in ----------
__global__ __launch_bounds__(256) void layerB64pool_k(
    const unsigned* __restrict__ tin, const float* __restrict__ partial2,
    const float* __restrict__ gamma, const float* __restrict__ beta, float invN,
    const float* __restrict__ W2, const float* __restrict__ b2,
    const int* __restrict__ batch,
    unsigned* __restrict__ maxb, float* __restrict__ sumb, int Nn)
{
    __shared__ float bnac[64];
    __shared__ float sd4[4][64];
    bn_prologue(partial2, gamma, beta, invN, bnac, sd4);

    int tid = threadIdx.x;
    int j = tid & 31, grp = tid >> 5;
    float a = bnac[j], c = bnac[32 + j];
    float wlo[32], whi[32];
#pragma unroll
    for (int k = 0; k < 32; k++) { wlo[k] = W2[k * 64 + j]; whi[k] = W2[k * 64 + 32 + j]; }
    float blo = b2[j], bhi = b2[32 + j];

    int n0 = (blockIdx.x * 8 + grp) * 64;
    if (n0 >= Nn) return;
    int nend = n0 + 64; if (nend > Nn) nend = Nn;

    int curg = -1;
    float mxl = 0.f, mxh = 0.f, sml = 0.f, smh = 0.f;
    for (int n = n0; n < nend; n++) {
        float2 tp = unpackf16(tin[(unsigned)n * 16u + (unsigned)(j >> 1)]);
        float t = (j & 1) ? tp.y : tp.x;
        float u = fmaxf(fmaf(a, t, c), 0.f);
        float olo = blo, ohi = bhi;
#pragma unroll
        for (int k = 0; k < 32; k++) {
            float uk = __shfl(u, k, 32);
            olo = fmaf(uk, wlo[k], olo);
            ohi = fmaf(uk, whi[k], ohi);
        }
        int gn = batch[n];
        if (gn != curg) {
            if (curg >= 0) {
                atomicMax(&maxb[curg * 64 + j], encf(mxl));
                atomicMax(&maxb[curg * 64 + 32 + j], encf(mxh));
                atomicAdd(&sumb[curg * 64 + j], sml);
                atomicAdd(&sumb[curg * 64 + 32 + j], smh);
            }
            curg = gn; mxl = olo; mxh = ohi; sml = olo; smh = ohi;
        } else {
            mxl = fmaxf(mxl, olo); mxh = fmaxf(mxh, ohi);
            sml += olo; smh += ohi;
        }
    }
    if (curg >= 0) {
        atomicMax(&maxb[curg * 64 + j], encf(mxl));
        atomicMax(&maxb[curg * 64 + 32 + j], encf(mxh));
        atomicAdd(&sumb[curg * 64 + j], sml);
        atomicAdd(&sumb[curg * 64 + 32 + j], smh);
    }
}

__global__ void final_k(const unsigned* __restrict__ maxb, const float* __restrict__ sumb,
                        const int* __restrict__ batch, int Nn, float* __restrict__ out)
{
    int g = blockIdx.x, tid = threadIdx.x;
    int a = 0, b = Nn;
    while (a < b) { int m = (a + b) >> 1; if (batch[m] < g) a = m + 1; else b = m; }
    int lo0 = a;
    a = 0; b = Nn;
    while (a < b) { int m = (a + b) >> 1; if (batch[m] < g + 1) a = m + 1; else b = m; }
    int hi0 = a;
    float inv = 1.f / fmaxf((float)(hi0 - lo0), 1.f);
    if (tid < 64) out[g * 128 + tid] = decf(maxb[g * 64 + tid]);
    else          out[g * 128 + tid] = sumb[g * 64 + (tid - 64)] * inv;
}

extern "C" void kernel_launch(void* const* d_in, const int* in_sizes, int n_in,
                              void* d_out, int out_size, void* d_ws, size_t ws_size,
                              hipStream_t stream) {
    const float* x    = (const float*)d_in[0];
    const int*   ei   = (const int*)d_in[1];
    const int*   ety  = (const int*)d_in[2];
    const int*   batch= (const int*)d_in[3];
    const float* emb  = (const float*)d_in[4];
    const float* W1s  = (const float*)d_in[5];
    const float* b1s  = (const float*)d_in[6];
    const float* g1s  = (const float*)d_in[7];
    const float* be1s = (const float*)d_in[8];
    const float* W2s  = (const float*)d_in[9];
    const float* b2s  = (const float*)d_in[10];
    const float* w15  = (const float*)d_in[11];
    const float* b15  = (const float*)d_in[12];
    const float* g5   = (const float*)d_in[13];
    const float* be5  = (const float*)d_in[14];
    const float* w25  = (const float*)d_in[15];
    const float* b25  = (const float*)d_in[16];

    int N = in_sizes[0] / 32;
    int E = in_sizes[1] / 2;
    int G = out_size / 128;

    int sBits = 1; while ((1 << sBits) < N + 1) sBits++;            // 18
    int bshift = 0; while (((N - 1) >> bshift) >= 512) bshift++;    // 9
    int nb2 = ((N - 1) >> bshift) + 1;                              // 391
    int nblkE = (E + 4095) / 4096;                                  // 977

    char* wsb = (char*)d_ws;
    size_t o = 0;
    size_t hPkBytes = (size_t)(N + 1) * 16 * 4;
    size_t tbBytes = (size_t)N * 16 * 4;                            // fp16 t
    size_t binBytes = (size_t)E * 4;
    size_t rtb = tbBytes > binBytes ? tbBytes : binBytes;
    unsigned* P      = (unsigned*)(wsb + o); o += hPkBytes;
    unsigned* Q      = (unsigned*)(wsb + o); o += hPkBytes;
    unsigned* tb     = (unsigned*)(wsb + o);
    unsigned* binned = (unsigned*)(wsb + o);        // alias: dead before layerA L0
    o += rtb;
    int*      rowptr = (int*)(wsb + o);   o += ((size_t)N + 2) * 4;
    unsigned* sorted = (unsigned*)(wsb + o); o += (size_t)E * 4;
    int*      chunkTot = (int*)(wsb + o); o += 1024;
    float*    partial  = (float*)(wsb + o); o += (size_t)NBLKA * 64 * 4;
    float*    partial2 = (float*)(wsb + o); o += 64 * 64 * 4;
    unsigned* maxb     = (unsigned*)(wsb + o); o += (size_t)G * 64 * 4;
    float*    sumb     = (float*)(wsb + o); o += (size_t)G * 64 * 4;
    int*      cntMat   = (int*)(wsb + o); o += (size_t)nb2 * nblkE * 4;

    // ---- CSR build ----
    passA_k<<<nblkE, 256, 0, stream>>>(ei + E, E, cntMat, bshift, nblkE, nb2);
    int total2 = nb2 * nblkE;
    int nchunk2 = (total2 + 2047) / 2048;
    scanA_k<<<nchunk2, 256, 0, stream>>>(cntMat, total2, chunkTot);
    scanC3_k<<<nchunk2, 256, 0, stream>>>(cntMat, total2, chunkTot, nchunk2);
    passB_k<<<nblkE, 256, 0, stream>>>(ei, ety, E, cntMat, binned, bshift, sBits, nblkE, nb2);
    passC_k<<<nb2, 256, 0, stream>>>(binned, cntMat, nblkE, rowptr, sorted, N, E, bshift, sBits, nb2);
    prep_k<<<(N * 16 + 255) / 256, 256, 0, stream>>>(x, P, Q, N, maxb, sumb, G * 64);

    unsigned sentw = (unsigned)N;
    float invN = 1.f / (float)N;

    // ---- 5 GINE layers (ping-pong P<->Q; bn_ac computed in layerB prologue) ----
    unsigned* inb = P;
    unsigned* outb = Q;
    for (int L = 0; L < 5; ++L) {
        const float* W1 = (L < 4) ? W1s + L * 1024 : w15;
        const float* b1 = (L < 4) ? b1s + L * 32  : b15;
        const float* ga = (L < 4) ? g1s + L * 32  : g5;
        const float* be = (L < 4) ? be1s + L * 32 : be5;
        const float* W2 = (L < 4) ? W2s + L * 1024 : w25;
        const float* b2 = (L < 4) ? b2s + L * 32  : b25;

        layerA_k<<<NBLKA, 256, 0, stream>>>(inb, rowptr, sorted, emb, W1, b1, tb, partial, N, sBits, sentw);
        bnred1_k<<<64, 256, 0, stream>>>(partial, partial2);
        if (L < 4) {
            layerB32_k<<<1024, 256, 0, stream>>>(tb, partial2, ga, be, invN, W2, b2, outb, N);
            unsigned* tmp = inb; inb = outb; outb = tmp;
        } else {
            layerB64pool_k<<<(N + 511) / 512, 256, 0, stream>>>(tb, partial2, ga, be, invN, W2, b2, batch, maxb, sumb, N);
        }
    }

    // ---- output ----
    final_k<<<G, 128, 0, stream>>>(maxb, sumb, batch, N, (float*)d_out);
}